// Round 23
// baseline (2354.104 us; speedup 1.0000x reference)
//
#include <hip/hip_runtime.h>
#include <hip/hip_bf16.h>
#include <math.h>

#define T_STEPS 512
#define BATCH   64
#define INDIM   1024
#define HDIM    1024
#define NWG     128      // recurrence (consumer) WGs; each owns 8 hidden cols
#define NPROD   128      // xproj producer WGs
#define HSLOT   16384    // u64 per packed slot (128KB); h uses 4-slot ring
#define XGSLOT  262144   // f32 per xg slot ([4096][64]); 8-slot ring

using bf16x8 = __attribute__((ext_vector_type(8))) __bf16;
using f32x4  = __attribute__((ext_vector_type(4))) float;
typedef unsigned long long u64;

struct WP {
    const float* wx[4];
    const float* wh[4];
    const float* bx[4];
    const float* bh[4];
};

// Pack 8 weight matrices into combined bf16 [4H][K] layouts + combined bias.
__global__ void pack_weights(WP p, __hip_bfloat16* __restrict__ Wx,
                             __hip_bfloat16* __restrict__ Wh, float* __restrict__ bias)
{
    int i = blockIdx.x * blockDim.x + threadIdx.x;
    const int stride = gridDim.x * blockDim.x;
    const int total = 4 * HDIM * INDIM;
    for (int idx = i; idx < total; idx += stride) {
        int g = idx >> 20;
        int r = idx & ((1 << 20) - 1);
        Wx[idx] = __float2bfloat16(p.wx[g][r]);
        Wh[idx] = __float2bfloat16(p.wh[g][r]);
    }
    if (i < 4 * HDIM) {
        int g = i >> 10, r = i & 1023;
        bias[i] = p.bx[g][r] + p.bh[g][r];
    }
}

// Cast inputs f32 -> bf16 AND pack into MFMA-fragment order (R16-proven):
// xbp[t][((wv*8+kk)*4+m)][lane][8 bf16],
//   element = x[t][16m+(lane&15)][256wv+32kk+8*(lane>>4)+i]
__global__ void cast_pack(const float* __restrict__ in, u64* __restrict__ xbp)
{
    const int total = T_STEPS * BATCH * (INDIM / 8);
    int i = blockIdx.x * blockDim.x + threadIdx.x;
    const int stride = gridDim.x * blockDim.x;
    for (; i < total; i += stride) {
        const int t  = i >> 13;
        const int r  = i & 8191;
        const int b  = r >> 7;
        const int j  = (r & 127) << 3;
        const float* src = in + ((size_t)t << 16) + (b << 10) + j;
        float4 v0 = *reinterpret_cast<const float4*>(src);
        float4 v1 = *reinterpret_cast<const float4*>(src + 4);
        union { __hip_bfloat16 bh[8]; u64 q[2]; } u;
        u.bh[0] = __float2bfloat16(v0.x); u.bh[1] = __float2bfloat16(v0.y);
        u.bh[2] = __float2bfloat16(v0.z); u.bh[3] = __float2bfloat16(v0.w);
        u.bh[4] = __float2bfloat16(v1.x); u.bh[5] = __float2bfloat16(v1.y);
        u.bh[6] = __float2bfloat16(v1.z); u.bh[7] = __float2bfloat16(v1.w);
        const int wv = j >> 8, kk = (j >> 5) & 7, lhi = (j >> 3) & 3;
        const int m = b >> 4, rA = b & 15;
        const int lane = (lhi << 4) + rA;
        const int blk  = (((wv << 3) + kk) << 2) + m;
        u64* d = xbp + ((size_t)t << 14) + (size_t)blk * 128 + (lane << 1);
        d[0] = u.q[0];
        d[1] = u.q[1];
    }
}

// h slot 0 init: MFMA-fragment-packed layout (R10-proven mapping).
__global__ void init_state(const float* __restrict__ H0, const float* __restrict__ C0,
                           __hip_bfloat16* __restrict__ hx, float* __restrict__ c)
{
    int i = blockIdx.x * blockDim.x + threadIdx.x;
    if (i < BATCH * HDIM) {
        int b = i >> 10, j = i & 1023;
        int m = b >> 4, rA = b & 15;
        int wv = j >> 8, kk = (j >> 5) & 7, lhi = (j >> 3) & 3, ii = j & 7;
        size_t idx = ((((size_t)(wv << 3) + kk) << 2) + m) * 512
                   + (((lhi << 4) + rA) << 3) + ii;
        hx[idx] = __float2bfloat16(H0[i]);
        c[i] = C0[i];
    }
}

__global__ void epilogue(const float* __restrict__ lasth, const float* __restrict__ c,
                         float* __restrict__ Hf, float* __restrict__ Cf)
{
    int i = blockIdx.x * blockDim.x + threadIdx.x;
    if (i < BATCH * HDIM) {
        Hf[i] = lasth[i];
        Cf[i] = c[i];
    }
}

__device__ __forceinline__ float fast_sigmoid(float x)
{
    return 1.f / (1.f + __expf(-x));
}
__device__ __forceinline__ float fast_tanh(float x)
{
    x = fminf(15.f, fmaxf(-15.f, x));
    const float e = __expf(2.f * x);
    return (e - 1.f) / (e + 1.f);
}

// Fused persistent LSTM, 512 threads/WG.
// WGs [0,128): consumers, 8 hidden cols each, K split across 8 WAVES
//   (R23: halves each wave's serial h-load stream + MFMA issue). Per-wave
//   eighth-flags; gates on waves 0-3 (same mapping as R20); xv pipelined
//   one step ahead; loads pinned with sched_barrier; 4-slot h ring.
// WGs [128,256): xproj producers (R17/R18-proven, tid<256 active).
__global__ __launch_bounds__(512, 1) void lstm_persist(
    const u64* __restrict__ xbp,             // [T][HSLOT] packed x
    const __hip_bfloat16* __restrict__ Wx,   // [4096][1024]
    const __hip_bfloat16* __restrict__ Wh,   // [4096][1024]
    const float* __restrict__ bias,          // [4096]
    u64* __restrict__ hx,                    // [4][HSLOT] packed h ring
    float* __restrict__ cbuf,                // [64][1024]
    float* __restrict__ out,                 // [T][64][1024]
    unsigned* __restrict__ hflags,           // [NWG*16]
    unsigned* __restrict__ xflags,           // [NPROD*16]
    float* __restrict__ xg)                  // [8][4096][64] ring (n-major)
{
    __shared__ float gl[8][64][33];          // per-wave partials (8 waves)
    __shared__ float hs[64][9];

    const int tid  = threadIdx.x;
    const int w    = tid >> 6;               // 0..7
    const int lane = tid & 63;
    const int rA   = lane & 15;
    const int kg   = (lane >> 4) << 3;
    const int bw   = blockIdx.x;

    if (bw >= NWG) {
        // ========== PRODUCER (R17/R18-proven; tid<256 active) ==========
        const int p   = bw - NWG;
        const int grp = p >> 5;
        const int pn  = p & 31;
        const int nb0 = pn << 7;

        for (int s = grp; s < T_STEPS; s += 4) {
            u64 aq[8][4][2];
            if (tid < 256) {
#pragma unroll
                for (int kk = 0; kk < 8; ++kk)
#pragma unroll
                    for (int m = 0; m < 4; ++m) {
                        const u64* q = xbp + ((size_t)s << 14)
                                     + ((((size_t)(w << 3) + kk) << 2) + m) * 128
                                     + (lane << 1);
                        aq[kk][m][0] = q[0];
                        aq[kk][m][1] = q[1];
                    }

                if (s >= 8) {   // ring WAR: all consumers past step s-8
                    const unsigned need = (unsigned)(s - 7);
                    const unsigned* f0 = hflags + lane * 16;
                    const unsigned* f1 = hflags + (lane + 64) * 16;
                    int guard = 1 << 18;
                    while (--guard > 0) {
                        int ok = (__hip_atomic_load(f0, __ATOMIC_RELAXED, __HIP_MEMORY_SCOPE_AGENT) >= need) &&
                                 (__hip_atomic_load(f1, __ATOMIC_RELAXED, __HIP_MEMORY_SCOPE_AGENT) >= need);
                        if (__all(ok)) break;
                        __builtin_amdgcn_s_sleep(1);
                    }
                }
            }

            float* xgs = xg + (size_t)(s & 7) * XGSLOT;
#pragma unroll 1
            for (int g32 = 0; g32 < 4; ++g32) {
                const int nb = nb0 + (g32 << 5);
                if (tid < 256) {
                    bf16x8 wxf[2][8];
#pragma unroll
                    for (int n2 = 0; n2 < 2; ++n2) {
                        const __hip_bfloat16* xr =
                            Wx + (size_t)(nb + (n2 << 4) + rA) * 1024 + (w << 8) + kg;
#pragma unroll
                        for (int kk = 0; kk < 8; ++kk)
                            wxf[n2][kk] = *reinterpret_cast<const bf16x8*>(xr + (kk << 5));
                    }
                    f32x4 acc[2][4] = {};
#pragma unroll
                    for (int kk = 0; kk < 8; ++kk)
#pragma unroll
                        for (int m = 0; m < 4; ++m) {
                            union { u64 q[2]; bf16x8 v; } c;
                            c.q[0] = aq[kk][m][0];
                            c.q[1] = aq[kk][m][1];
#pragma unroll
                            for (int n2 = 0; n2 < 2; ++n2)
                                acc[n2][m] = __builtin_amdgcn_mfma_f32_16x16x32_bf16(
                                    c.v, wxf[n2][kk], acc[n2][m], 0, 0, 0);
                        }
#pragma unroll
                    for (int n2 = 0; n2 < 2; ++n2)
#pragma unroll
                        for (int m = 0; m < 4; ++m) {
                            const int bb = (m << 4) + ((lane >> 4) << 2);
#pragma unroll
                            for (int r = 0; r < 4; ++r)
                                gl[w][bb + r][(n2 << 4) + rA] = acc[n2][m][r];
                        }
                }
                __syncthreads();
                if (tid < 256) {
                    const int np = tid >> 3;         // 0..31
                    const int bb = (tid & 7) << 3;   // 0..56
                    union { float f[8]; u64 q[4]; } v;
#pragma unroll
                    for (int i = 0; i < 8; ++i)
                        v.f[i] = gl[0][bb + i][np] + gl[1][bb + i][np]
                               + gl[2][bb + i][np] + gl[3][bb + i][np];
                    u64* d = (u64*)(xgs + (size_t)(nb + np) * 64 + bb);
#pragma unroll
                    for (int q4 = 0; q4 < 4; ++q4)
                        __hip_atomic_store(d + q4, v.q[q4],
                                           __ATOMIC_RELAXED, __HIP_MEMORY_SCOPE_AGENT);
                }
                __syncthreads();
            }
            if (tid == 0)
                __hip_atomic_store(&xflags[p * 16], (unsigned)(s + 1),
                                   __ATOMIC_RELAXED, __HIP_MEMORY_SCOPE_AGENT);
        }
        return;
    }

    // ================= CONSUMER (8-wave K-split) =================
    const int j0 = bw << 3;

    // Wave w's Wh fragments: K-eighth [128w,128w+128) of the 32 gate-rows.
    bf16x8 whf[2][4];
#pragma unroll
    for (int n2 = 0; n2 < 2; ++n2) {
        const int row  = (n2 << 4) + rA;
        const int grow = ((row >> 3) << 10) + j0 + (row & 7);
        const __hip_bfloat16* wr = Wh + ((size_t)grow << 10) + (w << 7) + kg;
#pragma unroll
        for (int kk = 0; kk < 4; ++kk)
            whf[n2][kk] = *reinterpret_cast<const bf16x8*>(wr + (kk << 5));
    }

    // Gate-phase state: waves 0-3 only (thread (b=lane, cols w*2+{0,1})).
    const int b = lane;
    float creg[2], brg[2][4];
    if (w < 4) {
#pragma unroll
        for (int e = 0; e < 2; ++e) {
            const int cl = (w << 1) + e;
            creg[e] = cbuf[(b << 10) + j0 + cl];
#pragma unroll
            for (int g = 0; g < 4; ++g) brg[e][g] = bias[(g << 10) + j0 + cl];
        }
    }

    const int pblk = (((bw >> 5) << 3) + ((bw >> 2) & 7)) << 2;
    const unsigned gsto = (unsigned)(pblk + (b >> 4)) * 256
                        + (unsigned)((((bw & 3) << 4) + (b & 15)) << 2) + w;
    // Wave w's eighth: h cols [128w,128w+128) = producers WGs [16w,16w+16).
    const unsigned* fq = hflags + (((w << 4) + (lane & 15)) << 4);

#define XV_FETCH(dst, ss)                                                      \
    do {                                                                       \
        const unsigned* fx_ = xflags +                                         \
            (((((unsigned)(ss) & 3) << 5) + (bw >> 4) + ((lane & 3) << 3)) << 4); \
        int guard_ = 1 << 18;                                                  \
        while (--guard_ > 0) {                                                 \
            unsigned v_ = __hip_atomic_load(fx_, __ATOMIC_RELAXED, __HIP_MEMORY_SCOPE_AGENT); \
            int ok_ = (lane < 4) ? (int)(v_ >= (unsigned)(ss) + 1) : 1;        \
            if (__all(ok_)) break;                                             \
            __builtin_amdgcn_s_sleep(1);                                       \
        }                                                                      \
        const float* xgs_ = xg + (size_t)((ss) & 7) * XGSLOT;                  \
        _Pragma("unroll") for (int e = 0; e < 2; ++e)                          \
        _Pragma("unroll") for (int g = 0; g < 4; ++g) {                        \
            unsigned uv_ = __hip_atomic_load(                                  \
                (const unsigned*)(xgs_ +                                       \
                    (size_t)((g << 10) + j0 + (w << 1) + e) * 64 + b),         \
                __ATOMIC_RELAXED, __HIP_MEMORY_SCOPE_AGENT);                   \
            dst[e][g] = __uint_as_float(uv_);                                  \
        }                                                                      \
    } while (0)

    float xv[2][4];
    if (w < 4) XV_FETCH(xv, 0);            // prologue: step 0's xv

    for (int s = 0; s < T_STEPS; ++s) {
        const unsigned t = (unsigned)s;
        const u64* hp = hx + (size_t)(t & 3) * HSLOT;
        u64*       hn = hx + (size_t)((t + 1) & 3) * HSLOT;

        // Per-wave wait: this wave's 16 eighth-producers at step t.
        {
            int guard = 1 << 18;
            while (--guard > 0) {
                unsigned v = __hip_atomic_load(fq, __ATOMIC_RELAXED, __HIP_MEMORY_SCOPE_AGENT);
                if (__all((int)(v >= t))) break;
                __builtin_amdgcn_s_sleep(1);
            }
        }

        // h-GEMM: wave's K-eighth = packed blocks 4w+kk (kk<4). All 32 u64
        // loads pinned before the 32 MFMAs.
        f32x4 acc[2][4] = {};
        {
            u64 aq[4][4][2];
#pragma unroll
            for (int kk = 0; kk < 4; ++kk)
#pragma unroll
                for (int m = 0; m < 4; ++m) {
                    const u64* q = hp + ((((size_t)(w << 2) + kk) << 2) + m) * 128
                                     + (lane << 1);
                    aq[kk][m][0] = __hip_atomic_load(q,     __ATOMIC_RELAXED, __HIP_MEMORY_SCOPE_AGENT);
                    aq[kk][m][1] = __hip_atomic_load(q + 1, __ATOMIC_RELAXED, __HIP_MEMORY_SCOPE_AGENT);
                }
            __builtin_amdgcn_sched_barrier(0);
#pragma unroll
            for (int kk = 0; kk < 4; ++kk)
#pragma unroll
                for (int m = 0; m < 4; ++m) {
                    union { u64 q[2]; bf16x8 v; } c;
                    c.q[0] = aq[kk][m][0];
                    c.q[1] = aq[kk][m][1];
#pragma unroll
                    for (int n2 = 0; n2 < 2; ++n2)
                        acc[n2][m] = __builtin_amdgcn_mfma_f32_16x16x32_bf16(
                            c.v, whf[n2][kk], acc[n2][m], 0, 0, 0);
                }
        }

#pragma unroll
        for (int n2 = 0; n2 < 2; ++n2)
#pragma unroll
            for (int m = 0; m < 4; ++m) {
                const int bb = (m << 4) + ((lane >> 4) << 2);
#pragma unroll
                for (int r = 0; r < 4; ++r)
                    gl[w][bb + r][(n2 << 4) + rA] = acc[n2][m][r];
            }
        __syncthreads();

        // Gates (waves 0-3): 8-partial reduce + direct packed h store.
        if (w < 4) {
            float hv[2];
#pragma unroll
            for (int e = 0; e < 2; ++e) {
                const int cl = (w << 1) + e;
                const int gr0 = cl;          // reused below per gate
                float gv[4];
#pragma unroll
                for (int g = 0; g < 4; ++g) {
                    const int gr = (g << 3) + gr0;
                    gv[g] = gl[0][b][gr] + gl[1][b][gr] + gl[2][b][gr] + gl[3][b][gr]
                          + gl[4][b][gr] + gl[5][b][gr] + gl[6][b][gr] + gl[7][b][gr]
                          + brg[e][g] + xv[e][g];
                }
                const float i_ = fast_sigmoid(gv[0]);
                const float f_ = fast_sigmoid(gv[1]);
                const float o_ = fast_sigmoid(gv[2]);
                const float ct = fast_tanh(gv[3]);
                const float cn = f_ * creg[e] + i_ * ct;
                creg[e] = cn;
                hv[e] = o_ * fast_tanh(cn);
                hs[b][cl] = hv[e];
            }
            union { __hip_bfloat16 bh[2]; unsigned u; } pk;
            pk.bh[0] = __float2bfloat16(hv[0]);
            pk.bh[1] = __float2bfloat16(hv[1]);
            __hip_atomic_store((unsigned*)hn + gsto, pk.u,
                               __ATOMIC_RELAXED, __HIP_MEMORY_SCOPE_AGENT);
        }
        __syncthreads();                     // h stores acked at MALL

        if (tid == 0)
            __hip_atomic_store(&hflags[bw * 16], t + 1,
                               __ATOMIC_RELAXED, __HIP_MEMORY_SCOPE_AGENT);

        // Prefetch next step's xv (off critical path). Then out stores.
        if (w < 4 && s + 1 < T_STEPS) XV_FETCH(xv, s + 1);

        if (tid < 64) {
            float v[8];
#pragma unroll
            for (int k = 0; k < 8; ++k) v[k] = hs[tid][k];
            float* orow = out + (((size_t)s << 6) + tid) * 1024 + j0;
            *reinterpret_cast<float4*>(orow)     = make_float4(v[0], v[1], v[2], v[3]);
            *reinterpret_cast<float4*>(orow + 4) = make_float4(v[4], v[5], v[6], v[7]);
        }
    }

    if (w < 4) {
#pragma unroll
        for (int e = 0; e < 2; ++e)
            cbuf[(b << 10) + j0 + (w << 1) + e] = creg[e];
    }
}

extern "C" void kernel_launch(void* const* d_in, const int* in_sizes, int n_in,
                              void* d_out, int out_size, void* d_ws, size_t ws_size,
                              hipStream_t stream)
{
    const float* inputs = (const float*)d_in[0];
    const float* H0     = (const float*)d_in[1];
    const float* C0     = (const float*)d_in[2];

    WP wp;
    wp.wx[0] = (const float*)d_in[3];  wp.bx[0] = (const float*)d_in[4];
    wp.wh[0] = (const float*)d_in[5];  wp.bh[0] = (const float*)d_in[6];
    wp.wx[1] = (const float*)d_in[7];  wp.bx[1] = (const float*)d_in[8];
    wp.wh[1] = (const float*)d_in[9];  wp.bh[1] = (const float*)d_in[10];
    wp.wx[2] = (const float*)d_in[11]; wp.bx[2] = (const float*)d_in[12];
    wp.wh[2] = (const float*)d_in[13]; wp.bh[2] = (const float*)d_in[14];
    wp.wx[3] = (const float*)d_in[15]; wp.bx[3] = (const float*)d_in[16];
    wp.wh[3] = (const float*)d_in[17]; wp.bh[3] = (const float*)d_in[18];

    char* ws = (char*)d_ws;
    size_t off = 0;
    auto alloc = [&](size_t bytes) {
        void* p = ws + off;
        off = (off + bytes + 255) & ~(size_t)255;
        return p;
    };
    __hip_bfloat16* Wx    = (__hip_bfloat16*)alloc((size_t)4 * HDIM * INDIM * 2);
    __hip_bfloat16* Wh    = (__hip_bfloat16*)alloc((size_t)4 * HDIM * HDIM * 2);
    float*          bias  = (float*)alloc((size_t)4 * HDIM * 4);
    u64*            xbp   = (u64*)alloc((size_t)T_STEPS * HSLOT * 8);   // 64MB
    u64*            hx    = (u64*)alloc((size_t)4 * HSLOT * 8);
    float*          cbuf  = (float*)alloc((size_t)BATCH * HDIM * 4);
    unsigned*       hflags= (unsigned*)alloc((size_t)NWG * 16 * 4);
    unsigned*       xflags= (unsigned*)alloc((size_t)NPROD * 16 * 4);
    float*          xg    = (float*)alloc((size_t)8 * XGSLOT * 4);      // 8MB
    if (off > ws_size) return;

    float* out = (float*)d_out;

    hipMemsetAsync(hflags, 0, (size_t)NWG * 16 * 4, stream);
    hipMemsetAsync(xflags, 0, (size_t)NPROD * 16 * 4, stream);
    hipLaunchKernelGGL(pack_weights, dim3(2048), dim3(256), 0, stream, wp, Wx, Wh, bias);
    hipLaunchKernelGGL(cast_pack, dim3(4096), dim3(256), 0, stream, inputs, xbp);
    hipLaunchKernelGGL(init_state, dim3(256), dim3(256), 0, stream,
                       H0, C0, (__hip_bfloat16*)hx, cbuf);

    hipLaunchKernelGGL(lstm_persist, dim3(NWG + NPROD), dim3(512), 0, stream,
                       (const u64*)xbp, (const __hip_bfloat16*)Wx,
                       (const __hip_bfloat16*)Wh, (const float*)bias,
                       hx, cbuf, out, hflags, xflags, xg);

    hipLaunchKernelGGL(epilogue, dim3(256), dim3(256), 0, stream,
                       out + (size_t)(T_STEPS - 1) * BATCH * HDIM, cbuf,
                       out + (size_t)T_STEPS * BATCH * HDIM,
                       out + (size_t)T_STEPS * BATCH * HDIM + BATCH * HDIM);
}

// Round 24
// 2330.784 us; speedup vs baseline: 1.0100x; 1.0100x over previous
//
#include <hip/hip_runtime.h>
#include <hip/hip_bf16.h>
#include <math.h>

#define T_STEPS 512
#define BATCH   64
#define INDIM   1024
#define HDIM    1024
#define NWG     128      // recurrence (consumer) WGs; each owns 8 hidden cols
#define NPROD   128      // xproj producer WGs
#define HSLOT   16384    // u64 per packed slot (128KB); h uses 4-slot ring
#define XGSLOT  262144   // f32 per xg slot ([4096][64]); 8-slot ring

using bf16x8 = __attribute__((ext_vector_type(8))) __bf16;
using f32x4  = __attribute__((ext_vector_type(4))) float;
typedef unsigned long long u64;

struct WP {
    const float* wx[4];
    const float* wh[4];
    const float* bx[4];
    const float* bh[4];
};

// Pack 8 weight matrices into combined bf16 [4H][K] layouts + combined bias.
__global__ void pack_weights(WP p, __hip_bfloat16* __restrict__ Wx,
                             __hip_bfloat16* __restrict__ Wh, float* __restrict__ bias)
{
    int i = blockIdx.x * blockDim.x + threadIdx.x;
    const int stride = gridDim.x * blockDim.x;
    const int total = 4 * HDIM * INDIM;
    for (int idx = i; idx < total; idx += stride) {
        int g = idx >> 20;
        int r = idx & ((1 << 20) - 1);
        Wx[idx] = __float2bfloat16(p.wx[g][r]);
        Wh[idx] = __float2bfloat16(p.wh[g][r]);
    }
    if (i < 4 * HDIM) {
        int g = i >> 10, r = i & 1023;
        bias[i] = p.bx[g][r] + p.bh[g][r];
    }
}

// Cast inputs f32 -> bf16 AND pack into MFMA-fragment order (R16-proven):
// xbp[t][((wv*8+kk)*4+m)][lane][8 bf16],
//   element = x[t][16m+(lane&15)][256wv+32kk+8*(lane>>4)+i]
__global__ void cast_pack(const float* __restrict__ in, u64* __restrict__ xbp)
{
    const int total = T_STEPS * BATCH * (INDIM / 8);
    int i = blockIdx.x * blockDim.x + threadIdx.x;
    const int stride = gridDim.x * blockDim.x;
    for (; i < total; i += stride) {
        const int t  = i >> 13;
        const int r  = i & 8191;
        const int b  = r >> 7;
        const int j  = (r & 127) << 3;
        const float* src = in + ((size_t)t << 16) + (b << 10) + j;
        float4 v0 = *reinterpret_cast<const float4*>(src);
        float4 v1 = *reinterpret_cast<const float4*>(src + 4);
        union { __hip_bfloat16 bh[8]; u64 q[2]; } u;
        u.bh[0] = __float2bfloat16(v0.x); u.bh[1] = __float2bfloat16(v0.y);
        u.bh[2] = __float2bfloat16(v0.z); u.bh[3] = __float2bfloat16(v0.w);
        u.bh[4] = __float2bfloat16(v1.x); u.bh[5] = __float2bfloat16(v1.y);
        u.bh[6] = __float2bfloat16(v1.z); u.bh[7] = __float2bfloat16(v1.w);
        const int wv = j >> 8, kk = (j >> 5) & 7, lhi = (j >> 3) & 3;
        const int m = b >> 4, rA = b & 15;
        const int lane = (lhi << 4) + rA;
        const int blk  = (((wv << 3) + kk) << 2) + m;
        u64* d = xbp + ((size_t)t << 14) + (size_t)blk * 128 + (lane << 1);
        d[0] = u.q[0];
        d[1] = u.q[1];
    }
}

// h slot 0 init: MFMA-fragment-packed layout (R10-proven mapping).
__global__ void init_state(const float* __restrict__ H0, const float* __restrict__ C0,
                           __hip_bfloat16* __restrict__ hx, float* __restrict__ c)
{
    int i = blockIdx.x * blockDim.x + threadIdx.x;
    if (i < BATCH * HDIM) {
        int b = i >> 10, j = i & 1023;
        int m = b >> 4, rA = b & 15;
        int wv = j >> 8, kk = (j >> 5) & 7, lhi = (j >> 3) & 3, ii = j & 7;
        size_t idx = ((((size_t)(wv << 3) + kk) << 2) + m) * 512
                   + (((lhi << 4) + rA) << 3) + ii;
        hx[idx] = __float2bfloat16(H0[i]);
        c[i] = C0[i];
    }
}

__global__ void epilogue(const float* __restrict__ lasth, const float* __restrict__ c,
                         float* __restrict__ Hf, float* __restrict__ Cf)
{
    int i = blockIdx.x * blockDim.x + threadIdx.x;
    if (i < BATCH * HDIM) {
        Hf[i] = lasth[i];
        Cf[i] = c[i];
    }
}

__device__ __forceinline__ float fast_sigmoid(float x)
{
    return 1.f / (1.f + __expf(-x));
}
__device__ __forceinline__ float fast_tanh(float x)
{
    x = fminf(15.f, fmaxf(-15.f, x));
    const float e = __expf(2.f * x);
    return (e - 1.f) / (e + 1.f);
}

// Fused persistent LSTM (R20 structure, best measured): grid = NWG + NPROD.
// WGs [0,128): consumers (8 cols each, per-wave quarter-flags, 4-slot h
//   ring, direct packed h stores, xv pipelined one step ahead, h-loads
//   pinned before MFMAs with sched_barrier).
// WGs [128,256): xproj producers, 4 steps ahead, 8-slot xg ring [n][b].
__global__ __launch_bounds__(256, 1) void lstm_persist(
    const u64* __restrict__ xbp,             // [T][HSLOT] packed x
    const __hip_bfloat16* __restrict__ Wx,   // [4096][1024]
    const __hip_bfloat16* __restrict__ Wh,   // [4096][1024]
    const float* __restrict__ bias,          // [4096]
    u64* __restrict__ hx,                    // [4][HSLOT] packed h ring
    float* __restrict__ cbuf,                // [64][1024]
    float* __restrict__ out,                 // [T][64][1024]
    unsigned* __restrict__ hflags,           // [NWG*16]
    unsigned* __restrict__ xflags,           // [NPROD*16]
    float* __restrict__ xg)                  // [8][4096][64] ring (n-major)
{
    __shared__ float gl[4][64][33];
    __shared__ float hs[64][9];

    const int tid  = threadIdx.x;
    const int w    = tid >> 6;
    const int lane = tid & 63;
    const int rA   = lane & 15;
    const int kg   = (lane >> 4) << 3;
    const int bw   = blockIdx.x;

    if (bw >= NWG) {
        // ================= PRODUCER (R17/R18-proven) =================
        const int p   = bw - NWG;
        const int grp = p >> 5;
        const int pn  = p & 31;
        const int nb0 = pn << 7;

        for (int s = grp; s < T_STEPS; s += 4) {
            u64 aq[8][4][2];
#pragma unroll
            for (int kk = 0; kk < 8; ++kk)
#pragma unroll
                for (int m = 0; m < 4; ++m) {
                    const u64* q = xbp + ((size_t)s << 14)
                                 + ((((size_t)(w << 3) + kk) << 2) + m) * 128
                                 + (lane << 1);
                    aq[kk][m][0] = q[0];
                    aq[kk][m][1] = q[1];
                }

            if (s >= 8) {   // ring WAR: all consumers past step s-8
                const unsigned need = (unsigned)(s - 7);
                const unsigned* f0 = hflags + lane * 16;
                const unsigned* f1 = hflags + (lane + 64) * 16;
                int guard = 1 << 18;
                while (--guard > 0) {
                    int ok = (__hip_atomic_load(f0, __ATOMIC_RELAXED, __HIP_MEMORY_SCOPE_AGENT) >= need) &&
                             (__hip_atomic_load(f1, __ATOMIC_RELAXED, __HIP_MEMORY_SCOPE_AGENT) >= need);
                    if (__all(ok)) break;
                    __builtin_amdgcn_s_sleep(1);
                }
            }

            float* xgs = xg + (size_t)(s & 7) * XGSLOT;
#pragma unroll 1
            for (int g32 = 0; g32 < 4; ++g32) {
                const int nb = nb0 + (g32 << 5);
                bf16x8 wxf[2][8];
#pragma unroll
                for (int n2 = 0; n2 < 2; ++n2) {
                    const __hip_bfloat16* xr =
                        Wx + (size_t)(nb + (n2 << 4) + rA) * 1024 + (w << 8) + kg;
#pragma unroll
                    for (int kk = 0; kk < 8; ++kk)
                        wxf[n2][kk] = *reinterpret_cast<const bf16x8*>(xr + (kk << 5));
                }
                f32x4 acc[2][4] = {};
#pragma unroll
                for (int kk = 0; kk < 8; ++kk)
#pragma unroll
                    for (int m = 0; m < 4; ++m) {
                        union { u64 q[2]; bf16x8 v; } c;
                        c.q[0] = aq[kk][m][0];
                        c.q[1] = aq[kk][m][1];
#pragma unroll
                        for (int n2 = 0; n2 < 2; ++n2)
                            acc[n2][m] = __builtin_amdgcn_mfma_f32_16x16x32_bf16(
                                c.v, wxf[n2][kk], acc[n2][m], 0, 0, 0);
                    }
#pragma unroll
                for (int n2 = 0; n2 < 2; ++n2)
#pragma unroll
                    for (int m = 0; m < 4; ++m) {
                        const int bb = (m << 4) + ((lane >> 4) << 2);
#pragma unroll
                        for (int r = 0; r < 4; ++r)
                            gl[w][bb + r][(n2 << 4) + rA] = acc[n2][m][r];
                    }
                __syncthreads();
                {
                    const int np = tid >> 3;         // 0..31
                    const int bb = (tid & 7) << 3;   // 0..56
                    union { float f[8]; u64 q[4]; } v;
#pragma unroll
                    for (int i = 0; i < 8; ++i)
                        v.f[i] = gl[0][bb + i][np] + gl[1][bb + i][np]
                               + gl[2][bb + i][np] + gl[3][bb + i][np];
                    u64* d = (u64*)(xgs + (size_t)(nb + np) * 64 + bb);
#pragma unroll
                    for (int q4 = 0; q4 < 4; ++q4)
                        __hip_atomic_store(d + q4, v.q[q4],
                                           __ATOMIC_RELAXED, __HIP_MEMORY_SCOPE_AGENT);
                }
                __syncthreads();
            }
            if (tid == 0)
                __hip_atomic_store(&xflags[p * 16], (unsigned)(s + 1),
                                   __ATOMIC_RELAXED, __HIP_MEMORY_SCOPE_AGENT);
        }
        return;
    }

    // ================= CONSUMER =================
    const int j0 = bw << 3;

    bf16x8 whf[2][8];
#pragma unroll
    for (int n2 = 0; n2 < 2; ++n2) {
        const int row  = (n2 << 4) + rA;
        const int grow = ((row >> 3) << 10) + j0 + (row & 7);
        const __hip_bfloat16* wr = Wh + ((size_t)grow << 10) + (w << 8) + kg;
#pragma unroll
        for (int kk = 0; kk < 8; ++kk)
            whf[n2][kk] = *reinterpret_cast<const bf16x8*>(wr + (kk << 5));
    }

    const int b = lane;
    float creg[2], brg[2][4];
#pragma unroll
    for (int e = 0; e < 2; ++e) {
        const int cl = (w << 1) + e;
        creg[e] = cbuf[(b << 10) + j0 + cl];
#pragma unroll
        for (int g = 0; g < 4; ++g) brg[e][g] = bias[(g << 10) + j0 + cl];
    }

    const int pblk = (((bw >> 5) << 3) + ((bw >> 2) & 7)) << 2;
    const unsigned gsto = (unsigned)(pblk + (b >> 4)) * 256
                        + (unsigned)((((bw & 3) << 4) + (b & 15)) << 2) + w;
    const unsigned* fq = hflags + (((w << 5) + (lane & 31)) << 4);

    // xv prefetch helper: poll this WG's 4 producers for step ss, then load.
#define XV_FETCH(dst, ss)                                                      \
    do {                                                                       \
        const unsigned* fx_ = xflags +                                         \
            (((((unsigned)(ss) & 3) << 5) + (bw >> 4) + ((lane & 3) << 3)) << 4); \
        int guard_ = 1 << 18;                                                  \
        while (--guard_ > 0) {                                                 \
            unsigned v_ = __hip_atomic_load(fx_, __ATOMIC_RELAXED, __HIP_MEMORY_SCOPE_AGENT); \
            int ok_ = (lane < 4) ? (int)(v_ >= (unsigned)(ss) + 1) : 1;        \
            if (__all(ok_)) break;                                             \
            __builtin_amdgcn_s_sleep(1);                                       \
        }                                                                      \
        const float* xgs_ = xg + (size_t)((ss) & 7) * XGSLOT;                  \
        _Pragma("unroll") for (int e = 0; e < 2; ++e)                          \
        _Pragma("unroll") for (int g = 0; g < 4; ++g) {                        \
            unsigned uv_ = __hip_atomic_load(                                  \
                (const unsigned*)(xgs_ +                                       \
                    (size_t)((g << 10) + j0 + (w << 1) + e) * 64 + b),         \
                __ATOMIC_RELAXED, __HIP_MEMORY_SCOPE_AGENT);                   \
            dst[e][g] = __uint_as_float(uv_);                                  \
        }                                                                      \
    } while (0)

    float xv[2][4];
    XV_FETCH(xv, 0);            // prologue: step 0's xv

    for (int s = 0; s < T_STEPS; ++s) {
        const unsigned t = (unsigned)s;
        const u64* hp = hx + (size_t)(t & 3) * HSLOT;
        u64*       hn = hx + (size_t)((t + 1) & 3) * HSLOT;

        // Per-wave wait: this wave's 32 quarter-producers at step t.
        {
            int guard = 1 << 18;
            while (--guard > 0) {
                unsigned v = __hip_atomic_load(fq, __ATOMIC_RELAXED, __HIP_MEMORY_SCOPE_AGENT);
                if (__all((int)(v >= t))) break;
                __builtin_amdgcn_s_sleep(1);
            }
        }

        // h-GEMM: ALL 64 u64 loads issued first (pinned by sched_barrier),
        // then all MFMAs -> single exposed MALL latency.
        f32x4 acc[2][4] = {};
        {
            u64 aq[8][4][2];
#pragma unroll
            for (int kk = 0; kk < 8; ++kk)
#pragma unroll
                for (int m = 0; m < 4; ++m) {
                    const u64* q = hp + ((((size_t)(w << 3) + kk) << 2) + m) * 128
                                     + (lane << 1);
                    aq[kk][m][0] = __hip_atomic_load(q,     __ATOMIC_RELAXED, __HIP_MEMORY_SCOPE_AGENT);
                    aq[kk][m][1] = __hip_atomic_load(q + 1, __ATOMIC_RELAXED, __HIP_MEMORY_SCOPE_AGENT);
                }
            __builtin_amdgcn_sched_barrier(0);
#pragma unroll
            for (int kk = 0; kk < 8; ++kk)
#pragma unroll
                for (int m = 0; m < 4; ++m) {
                    union { u64 q[2]; bf16x8 v; } c;
                    c.q[0] = aq[kk][m][0];
                    c.q[1] = aq[kk][m][1];
#pragma unroll
                    for (int n2 = 0; n2 < 2; ++n2)
                        acc[n2][m] = __builtin_amdgcn_mfma_f32_16x16x32_bf16(
                            c.v, whf[n2][kk], acc[n2][m], 0, 0, 0);
                }
        }

#pragma unroll
        for (int n2 = 0; n2 < 2; ++n2)
#pragma unroll
            for (int m = 0; m < 4; ++m) {
                const int bb = (m << 4) + ((lane >> 4) << 2);
#pragma unroll
                for (int r = 0; r < 4; ++r)
                    gl[w][bb + r][(n2 << 4) + rA] = acc[n2][m][r];
            }
        __syncthreads();

        // Gates + direct packed h store (uses prefetched xv).
        {
            float hv[2];
#pragma unroll
            for (int e = 0; e < 2; ++e) {
                const int cl = (w << 1) + e;
                float gv[4];
#pragma unroll
                for (int g = 0; g < 4; ++g)
                    gv[g] = gl[0][b][(g << 3) + cl] + gl[1][b][(g << 3) + cl]
                          + gl[2][b][(g << 3) + cl] + gl[3][b][(g << 3) + cl]
                          + brg[e][g] + xv[e][g];
                const float i_ = fast_sigmoid(gv[0]);
                const float f_ = fast_sigmoid(gv[1]);
                const float o_ = fast_sigmoid(gv[2]);
                const float ct = fast_tanh(gv[3]);
                const float cn = f_ * creg[e] + i_ * ct;
                creg[e] = cn;
                hv[e] = o_ * fast_tanh(cn);
                hs[b][cl] = hv[e];
            }
            union { __hip_bfloat16 bh[2]; unsigned u; } pk;
            pk.bh[0] = __float2bfloat16(hv[0]);
            pk.bh[1] = __float2bfloat16(hv[1]);
            __hip_atomic_store((unsigned*)hn + gsto, pk.u,
                               __ATOMIC_RELAXED, __HIP_MEMORY_SCOPE_AGENT);
        }
        __syncthreads();                     // h stores acked at MALL

        if (tid == 0)
            __hip_atomic_store(&hflags[bw * 16], t + 1,
                               __ATOMIC_RELAXED, __HIP_MEMORY_SCOPE_AGENT);

        // Prefetch next step's xv (producers ~4 ahead: poll hits at once;
        // loads have a full iteration to land). Then out stores.
        if (s + 1 < T_STEPS) XV_FETCH(xv, s + 1);

        if (tid < 64) {
            float v[8];
#pragma unroll
            for (int k = 0; k < 8; ++k) v[k] = hs[tid][k];
            float* orow = out + (((size_t)s << 6) + tid) * 1024 + j0;
            *reinterpret_cast<float4*>(orow)     = make_float4(v[0], v[1], v[2], v[3]);
            *reinterpret_cast<float4*>(orow + 4) = make_float4(v[4], v[5], v[6], v[7]);
        }
    }

#pragma unroll
    for (int e = 0; e < 2; ++e)
        cbuf[(b << 10) + j0 + (w << 1) + e] = creg[e];
}

extern "C" void kernel_launch(void* const* d_in, const int* in_sizes, int n_in,
                              void* d_out, int out_size, void* d_ws, size_t ws_size,
                              hipStream_t stream)
{
    const float* inputs = (const float*)d_in[0];
    const float* H0     = (const float*)d_in[1];
    const float* C0     = (const float*)d_in[2];

    WP wp;
    wp.wx[0] = (const float*)d_in[3];  wp.bx[0] = (const float*)d_in[4];
    wp.wh[0] = (const float*)d_in[5];  wp.bh[0] = (const float*)d_in[6];
    wp.wx[1] = (const float*)d_in[7];  wp.bx[1] = (const float*)d_in[8];
    wp.wh[1] = (const float*)d_in[9];  wp.bh[1] = (const float*)d_in[10];
    wp.wx[2] = (const float*)d_in[11]; wp.bx[2] = (const float*)d_in[12];
    wp.wh[2] = (const float*)d_in[13]; wp.bh[2] = (const float*)d_in[14];
    wp.wx[3] = (const float*)d_in[15]; wp.bx[3] = (const float*)d_in[16];
    wp.wh[3] = (const float*)d_in[17]; wp.bh[3] = (const float*)d_in[18];

    char* ws = (char*)d_ws;
    size_t off = 0;
    auto alloc = [&](size_t bytes) {
        void* p = ws + off;
        off = (off + bytes + 255) & ~(size_t)255;
        return p;
    };
    __hip_bfloat16* Wx    = (__hip_bfloat16*)alloc((size_t)4 * HDIM * INDIM * 2);
    __hip_bfloat16* Wh    = (__hip_bfloat16*)alloc((size_t)4 * HDIM * HDIM * 2);
    float*          bias  = (float*)alloc((size_t)4 * HDIM * 4);
    u64*            xbp   = (u64*)alloc((size_t)T_STEPS * HSLOT * 8);   // 64MB
    u64*            hx    = (u64*)alloc((size_t)4 * HSLOT * 8);
    float*          cbuf  = (float*)alloc((size_t)BATCH * HDIM * 4);
    unsigned*       hflags= (unsigned*)alloc((size_t)NWG * 16 * 4);
    unsigned*       xflags= (unsigned*)alloc((size_t)NPROD * 16 * 4);
    float*          xg    = (float*)alloc((size_t)8 * XGSLOT * 4);      // 8MB
    if (off > ws_size) return;

    float* out = (float*)d_out;

    hipMemsetAsync(hflags, 0, (size_t)NWG * 16 * 4, stream);
    hipMemsetAsync(xflags, 0, (size_t)NPROD * 16 * 4, stream);
    hipLaunchKernelGGL(pack_weights, dim3(2048), dim3(256), 0, stream, wp, Wx, Wh, bias);
    hipLaunchKernelGGL(cast_pack, dim3(4096), dim3(256), 0, stream, inputs, xbp);
    hipLaunchKernelGGL(init_state, dim3(256), dim3(256), 0, stream,
                       H0, C0, (__hip_bfloat16*)hx, cbuf);

    hipLaunchKernelGGL(lstm_persist, dim3(NWG + NPROD), dim3(256), 0, stream,
                       (const u64*)xbp, (const __hip_bfloat16*)Wx,
                       (const __hip_bfloat16*)Wh, (const float*)bias,
                       hx, cbuf, out, hflags, xflags, xg);

    hipLaunchKernelGGL(epilogue, dim3(256), dim3(256), 0, stream,
                       out + (size_t)(T_STEPS - 1) * BATCH * HDIM, cbuf,
                       out + (size_t)T_STEPS * BATCH * HDIM,
                       out + (size_t)T_STEPS * BATCH * HDIM + BATCH * HDIM);
}